// Round 1
// baseline (720.810 us; speedup 1.0000x reference)
//
#include <hip/hip_runtime.h>

// Problem constants (fixed by the reference module).
constexpr int B = 4, C = 256, H = 256, W = 512;
constexpr int MAXLOAD = 100, FS = 14;
constexpr int NROI = B * MAXLOAD;            // 400
constexpr int HB = B * H;                    // 1024 (flattened b*h rows)
constexpr int FS2 = FS * FS;                 // 196
constexpr int MAIN = NROI * C * FS2;         // 20,070,400 elements of out[0]
constexpr int MAIN_BLOCKS = MAIN / 256;      // 78,400 (exact)
constexpr int NXCD = 8;
constexpr int CHUNK = MAIN_BLOCKS / NXCD;    // 9,800 (MAIN_BLOCKS % 8 == 0 -> bijective)

__global__ __launch_bounds__(256) void pooler_kernel(
    const float* __restrict__ feats,   // (B,C,H,W) fp32
    const float* __restrict__ rois,    // (B*MAXLOAD, 4) fp32: x0,y0,x1,y1
    float* __restrict__ out)           // (NROI,C,FS,FS) fp32 ++ val_bind(NROI) as fp32
{
    int bid = blockIdx.x;

    if (bid >= MAIN_BLOCKS) {
        // val_bind tail: repeat(arange(B), MAXLOAD), written as float
        int t = (bid - MAIN_BLOCKS) * 256 + threadIdx.x;
        if (t < NROI)
            __builtin_nontemporal_store((float)(t / MAXLOAD), &out[MAIN + t]);
        return;
    }

    // XCD-chunk swizzle: blocks round-robin XCDs in dispatch order, so giving
    // XCD i the contiguous chunk [i*CHUNK, (i+1)*CHUNK) keeps each XCD's
    // private L2 on its own 32-channel slice. Bijective because MAIN_BLOCKS%8==0.
    int wg = (bid % NXCD) * CHUNK + bid / NXCD;
    int e  = wg * 256 + threadIdx.x;

    // c-major decomposition: e = (c*NROI + n)*FS2 + pos.
    // Concurrent blocks share a few channels across all 400 ROIs -> the
    // (b,c) feature slices they gather from stay L2-resident (cross-ROI reuse).
    int pos = e % FS2;
    int qq  = e / FS2;
    int n   = qq % NROI;
    int c   = qq / NROI;
    int fx  = pos % FS;
    int fy  = pos / FS;
    int vb  = n / MAXLOAD;   // batch of this roi

    float4 roi = reinterpret_cast<const float4*>(rois)[n];
    float scalex = roi.z - roi.x;
    float scaley = roi.w - roi.y;
    float biasx  = roi.x;
    float biasy  = roi.y + (float)vb * 1024.0f;  // image_height = 1024

    // grid coords (dscale = 4)
    float gridx = ((float)fx * (1.0f / 13.0f) * scalex + biasx) * 0.25f;
    float gridy = ((float)fy * (1.0f / 13.0f) * scaley + biasy) * 0.25f;

    // px = gridx * W/(W-1) - 0.5 ; py = gridy * HB/(HB-1) - 0.5 (algebraic
    // simplification of the reference's normalize->denormalize round trip;
    // bilinear is continuous so fp reordering is harmless)
    float px = gridx * (512.0f / 511.0f) - 0.5f;
    float py = gridy * (1024.0f / 1023.0f) - 0.5f;
    px = fminf(fmaxf(px, 0.0f), (float)(W - 1));
    py = fminf(fmaxf(py, 0.0f), (float)(HB - 1));

    float x0f = floorf(px), y0f = floorf(py);
    float wx = px - x0f, wy = py - y0f;
    int x0 = (int)x0f, y0 = (int)y0f;
    int x1 = min(x0 + 1, W - 1);
    int y1 = min(y0 + 1, HB - 1);

    // feats viewed as (C, HB, W): flat = ((y>>8)*C*H + (y&255))*W + c*H*W + x
    int cb  = c * (H * W);
    int ro0 = ((y0 >> 8) * (C * H) + (y0 & (H - 1))) * W + cb;
    int ro1 = ((y1 >> 8) * (C * H) + (y1 & (H - 1))) * W + cb;

    float f00 = feats[ro0 + x0];
    float f01 = feats[ro0 + x1];
    float f10 = feats[ro1 + x0];
    float f11 = feats[ro1 + x1];

    float v0 = f00 + wx * (f01 - f00);
    float v1 = f10 + wx * (f11 - f10);
    float res = v0 + wy * (v1 - v0);

    // Write-once streaming output: non-temporal so it doesn't evict the
    // feature lines we want resident in L2 for cross-ROI reuse.
    int out_idx = (n * C + c) * FS2 + pos;
    __builtin_nontemporal_store(res, &out[out_idx]);
}

extern "C" void kernel_launch(void* const* d_in, const int* in_sizes, int n_in,
                              void* d_out, int out_size, void* d_ws, size_t ws_size,
                              hipStream_t stream) {
    const float* feats = (const float*)d_in[0];
    const float* rois  = (const float*)d_in[1];
    float* out = (float*)d_out;

    int tail_blocks = (NROI + 255) / 256;               // 2
    pooler_kernel<<<MAIN_BLOCKS + tail_blocks, 256, 0, stream>>>(feats, rois, out);
}